// Round 4
// baseline (824.743 us; speedup 1.0000x reference)
//
#include <hip/hip_runtime.h>

#define HW (512 * 512)
#define NBINS 256
#define NKEYS 512          // key = bin*2 + side (side = col>=256), bins 4..255 valid
#define NB 128             // batch
#define SORT_BLOCKS 256    // each sort block handles 1024 px
#define K_PER_LANE 16      // consecutive perm entries per lane in pass1s

// ---------------- workspace layout (bytes) ----------------
// 0       : rowSum[512]  int   (per-key total count)
// 2048    : base[512]    int   (exclusive prefix of rowSum)
// 4096    : totalValid   int
// 8192    : S1[128][256] float (zeroed by memset)
// 139264  : S2[128][256] float (zeroed by memset)
// 270336  : blockHist[512][256] int  -> becomes per-(key,block) exclusive prefix
// 794624  : perm[HW]     int   packed (key<<18 | px)
// total ~1.76 MB

// ---- kernel 1: per-block histogram over 512 keys ----
__global__ __launch_bounds__(256) void keyhist(const int* __restrict__ bins,
                                               int* __restrict__ blockHist) {
    __shared__ int h[NKEYS];
    const int tid = threadIdx.x;
    h[tid] = 0; h[tid + 256] = 0;
    __syncthreads();
    const int blk = blockIdx.x;
    int4 v = ((const int4*)bins)[blk * 256 + tid];
    int pxb = (blk * 256 + tid) * 4;
    int bv[4] = {v.x, v.y, v.z, v.w};
    #pragma unroll
    for (int k = 0; k < 4; ++k) {
        int bn = bv[k];
        if (bn > 3 && bn < NBINS) {
            int col = (pxb + k) & 511;
            atomicAdd(&h[bn * 2 + (col >= 256 ? 1 : 0)], 1);
        }
    }
    __syncthreads();
    blockHist[tid * SORT_BLOCKS + blk] = h[tid];
    blockHist[(tid + 256) * SORT_BLOCKS + blk] = h[tid + 256];
}

// ---- kernel 2: per-key exclusive scan across blocks; rowSum[key] = total ----
__global__ __launch_bounds__(256) void rowscan(int* __restrict__ blockHist,
                                               int* __restrict__ rowSum) {
    __shared__ int sc[256];
    const int key = blockIdx.x;
    const int t = threadIdx.x;
    int v = blockHist[key * SORT_BLOCKS + t];
    sc[t] = v;
    __syncthreads();
    for (int off = 1; off < 256; off <<= 1) {
        int x = (t >= off) ? sc[t - off] : 0;
        __syncthreads();
        sc[t] += x;
        __syncthreads();
    }
    blockHist[key * SORT_BLOCKS + t] = sc[t] - v;   // exclusive
    if (t == 255) rowSum[key] = sc[255];
}

// ---- kernel 3: exclusive scan over rowSum[512] -> base; write totalValid ----
__global__ __launch_bounds__(512) void basescan(const int* __restrict__ rowSum,
                                                int* __restrict__ base,
                                                int* __restrict__ totalValid) {
    __shared__ int sc[NKEYS];
    const int t = threadIdx.x;
    int v = rowSum[t];
    sc[t] = v;
    __syncthreads();
    for (int off = 1; off < NKEYS; off <<= 1) {
        int x = (t >= off) ? sc[t - off] : 0;
        __syncthreads();
        sc[t] += x;
        __syncthreads();
    }
    base[t] = sc[t] - v;
    if (t == NKEYS - 1) *totalValid = sc[NKEYS - 1];
}

// ---- kernel 4: scatter pixel indices into ring-ordered perm ----
__global__ __launch_bounds__(256) void scatter(const int* __restrict__ bins,
                                               const int* __restrict__ blockHist,
                                               const int* __restrict__ base,
                                               int* __restrict__ perm) {
    __shared__ int cursor[NKEYS];
    const int tid = threadIdx.x;
    const int blk = blockIdx.x;
    cursor[tid] = base[tid] + blockHist[tid * SORT_BLOCKS + blk];
    cursor[tid + 256] = base[tid + 256] + blockHist[(tid + 256) * SORT_BLOCKS + blk];
    __syncthreads();
    int4 v = ((const int4*)bins)[blk * 256 + tid];
    int pxb = (blk * 256 + tid) * 4;
    int bv[4] = {v.x, v.y, v.z, v.w};
    #pragma unroll
    for (int k = 0; k < 4; ++k) {
        int bn = bv[k];
        if (bn > 3 && bn < NBINS) {
            int px = pxb + k;
            int key = bn * 2 + ((px & 511) >= 256 ? 1 : 0);
            int pos = atomicAdd(&cursor[key], 1);
            perm[pos] = (key << 18) | px;
        }
    }
}

// ---- kernel 5: main pass — ring-ordered, register-accumulated S1/S2 ----
__global__ __launch_bounds__(256) void pass1s(const float* __restrict__ parts,
                                              const float* __restrict__ projs,
                                              const int* __restrict__ perm,
                                              const int* __restrict__ totalValid,
                                              float* __restrict__ S1,
                                              float* __restrict__ S2) {
    __shared__ float hist[2 * NBINS];   // [0..255]=s1, [256..511]=s2
    const int tid = threadIdx.x;
    hist[tid] = 0.f; hist[tid + 256] = 0.f;
    __syncthreads();

    const int total = *totalValid;
    const int b = blockIdx.y;
    const float* __restrict__ P = parts + (size_t)b * HW;
    const float* __restrict__ Q = projs + (size_t)b * HW;

    const int baseE = (blockIdx.x * 256 + tid) * K_PER_LANE;
    float a1 = 0.f, a2 = 0.f;
    int curBin = -1;

    if (baseE < total) {
        #pragma unroll
        for (int g = 0; g < K_PER_LANE / 4; ++g) {
            int4 e4 = *(const int4*)(perm + baseE + g * 4);   // 16B aligned; OOB entries guarded below
            int ee[4] = {e4.x, e4.y, e4.z, e4.w};
            #pragma unroll
            for (int k = 0; k < 4; ++k) {
                int pos = baseE + g * 4 + k;
                if (pos < total) {
                    int e = ee[k];
                    int bin = e >> 19;          // key>>1
                    int px = e & 0x3FFFF;
                    float n = P[px] - Q[px];
                    if (bin != curBin) {
                        if (curBin >= 0) {
                            atomicAdd(&hist[curBin], a1);
                            atomicAdd(&hist[NBINS + curBin], a2);
                        }
                        curBin = bin; a1 = 0.f; a2 = 0.f;
                    }
                    a1 += fabsf(n);
                    a2 += n * n;
                }
            }
        }
        if (curBin >= 0) {
            atomicAdd(&hist[curBin], a1);
            atomicAdd(&hist[NBINS + curBin], a2);
        }
    }
    __syncthreads();
    unsafeAtomicAdd(&S1[b * NBINS + tid], hist[tid]);
    unsafeAtomicAdd(&S2[b * NBINS + tid], hist[tid + 256]);
}

// ---- finalize: per-batch closed-form sum over bins ----
__global__ __launch_bounds__(256) void finalize(const float* __restrict__ S1,
                                                const float* __restrict__ S2,
                                                const int* __restrict__ rowSum,
                                                float* __restrict__ out) {
    const int b = blockIdx.x;
    const int t = threadIdx.x;
    float contrib = 0.f;
    if (t > 3) {   // valid bins 4..255
        float c = (float)(rowSum[t * 2] + rowSum[t * 2 + 1]);
        float s1 = S1[b * NBINS + t];
        float s2 = S2[b * NBINS + t];
        float mean = s1 / fmaxf(c, 1.f);
        float ssq = fmaxf(s2 - mean * s1, 0.f);          // = sum (a - mean)^2
        float var = ssq / fmaxf(c - 1.f, 1.f);
        contrib = -0.5f * s2 / var - c * logf(6.283185307179586f * var);
    }
    #pragma unroll
    for (int off = 32; off > 0; off >>= 1) contrib += __shfl_down(contrib, off, 64);
    __shared__ float w[4];
    if ((t & 63) == 0) w[t >> 6] = contrib;
    __syncthreads();
    if (t == 0) out[b] = w[0] + w[1] + w[2] + w[3];
}

extern "C" void kernel_launch(void* const* d_in, const int* in_sizes, int n_in,
                              void* d_out, int out_size, void* d_ws, size_t ws_size,
                              hipStream_t stream) {
    const float* parts = (const float*)d_in[0];
    const float* projs = (const float*)d_in[1];
    const int* bins    = (const int*)d_in[2];
    float* out = (float*)d_out;

    char* ws = (char*)d_ws;
    int*   rowSum     = (int*)(ws + 0);
    int*   base       = (int*)(ws + 2048);
    int*   totalValid = (int*)(ws + 4096);
    float* S1         = (float*)(ws + 8192);
    float* S2         = (float*)(ws + 139264);
    int*   blockHist  = (int*)(ws + 270336);
    int*   perm       = (int*)(ws + 794624);

    // zero S1,S2 (everything else is fully written before read)
    hipMemsetAsync(S1, 0, 2 * (size_t)NB * NBINS * sizeof(float), stream);

    keyhist <<<SORT_BLOCKS, 256, 0, stream>>>(bins, blockHist);
    rowscan <<<NKEYS, 256, 0, stream>>>(blockHist, rowSum);
    basescan<<<1, NKEYS, 0, stream>>>(rowSum, base, totalValid);
    scatter <<<SORT_BLOCKS, 256, 0, stream>>>(bins, blockHist, base, perm);
    // 64 x-blocks cover HW/(256*16)=64 worst case; blocks past totalValid idle out
    pass1s  <<<dim3(HW / (256 * K_PER_LANE), NB), 256, 0, stream>>>(parts, projs, perm,
                                                                   totalValid, S1, S2);
    finalize<<<NB, 256, 0, stream>>>(S1, S2, rowSum, out);
}

// Round 5
// 304.109 us; speedup vs baseline: 2.7120x; 2.7120x over previous
//
#include <hip/hip_runtime.h>

#define HW (512 * 512)
#define NBINS 256
#define NB 128
#define NTILES 64          // 8x8 tiles of 64x64
#define TPX 4096           // pixels per tile

// ---------------- workspace layout (bytes) ----------------
// 0      : tileCount[64]   int
// 512    : counts[256]     int   (per-bin totals, batch-independent)
// 4096   : S1[128][256]    float
// 135168 : S2[128][256]    float
// 266240 : perm[64][4096]  int   packed (bin<<12 | local)

// ---- kernel 1 (once per launch): counting-sort each tile's pixels by bin ----
__global__ __launch_bounds__(256) void tilesort(const int* __restrict__ bins,
                                                int* __restrict__ perm,
                                                int* __restrict__ tileCount,
                                                int* __restrict__ counts) {
    __shared__ int hist[NBINS];
    __shared__ int sc[NBINS];
    __shared__ int cursor[NBINS];
    const int t = threadIdx.x;
    const int tile = blockIdx.x;
    const int trow = tile >> 3, tcol = tile & 7;
    hist[t] = 0;
    __syncthreads();

    int myBins[16];
    #pragma unroll
    for (int k = 0; k < 4; ++k) {
        int row = (t >> 4) + k * 16;
        int col4 = t & 15;
        int4 v = *(const int4*)&bins[(trow * 64 + row) * 512 + tcol * 64 + col4 * 4];
        int bb[4] = {v.x, v.y, v.z, v.w};
        #pragma unroll
        for (int m = 0; m < 4; ++m) {
            myBins[k * 4 + m] = bb[m];
            if (bb[m] > 3 && bb[m] < NBINS) atomicAdd(&hist[bb[m]], 1);
        }
    }
    __syncthreads();
    // inclusive scan of hist -> sc
    sc[t] = hist[t];
    __syncthreads();
    for (int off = 1; off < 256; off <<= 1) {
        int x = (t >= off) ? sc[t - off] : 0;
        __syncthreads();
        sc[t] += x;
        __syncthreads();
    }
    cursor[t] = sc[t] - hist[t];     // exclusive prefix
    if (t == 255) tileCount[tile] = sc[255];
    if (hist[t]) atomicAdd(&counts[t], hist[t]);
    __syncthreads();

    #pragma unroll
    for (int k = 0; k < 4; ++k) {
        int row = (t >> 4) + k * 16;
        int col4 = t & 15;
        #pragma unroll
        for (int m = 0; m < 4; ++m) {
            int bn = myBins[k * 4 + m];
            if (bn > 3 && bn < NBINS) {
                int local = row * 64 + col4 * 4 + m;
                int pos = atomicAdd(&cursor[bn], 1);
                perm[tile * TPX + pos] = (bn << 12) | local;
            }
        }
    }
}

// ---- kernel 2: main pass — LDS-staged tile, bin-sorted register runs ----
__global__ __launch_bounds__(256) void pass(const float* __restrict__ parts,
                                            const float* __restrict__ projs,
                                            const int* __restrict__ perm,
                                            const int* __restrict__ tileCount,
                                            float* __restrict__ S1,
                                            float* __restrict__ S2) {
    __shared__ float sP[TPX], sQ[TPX];
    __shared__ float h1[NBINS], h2[NBINS];
    const int t = threadIdx.x;
    const int tile = blockIdx.x;
    const int b = blockIdx.y;
    const int trow = tile >> 3, tcol = tile & 7;
    h1[t] = 0.f; h2[t] = 0.f;

    const float* __restrict__ P = parts + (size_t)b * HW;
    const float* __restrict__ Q = projs + (size_t)b * HW;

    // stage tile: coalesced 256B row segments; XOR-swizzle slot so vertical
    // arcs (constant col) spread across banks in the gather phase
    #pragma unroll
    for (int k = 0; k < 4; ++k) {
        int row = (t >> 4) + k * 16;
        int col4 = t & 15;
        const float4 p = *(const float4*)&P[(trow * 64 + row) * 512 + tcol * 64 + col4 * 4];
        const float4 q = *(const float4*)&Q[(trow * 64 + row) * 512 + tcol * 64 + col4 * 4];
        int x = row & 31;
        int rb = row * 64;
        sP[rb + ((col4 * 4 + 0) ^ x)] = p.x;
        sP[rb + ((col4 * 4 + 1) ^ x)] = p.y;
        sP[rb + ((col4 * 4 + 2) ^ x)] = p.z;
        sP[rb + ((col4 * 4 + 3) ^ x)] = p.w;
        sQ[rb + ((col4 * 4 + 0) ^ x)] = q.x;
        sQ[rb + ((col4 * 4 + 1) ^ x)] = q.y;
        sQ[rb + ((col4 * 4 + 2) ^ x)] = q.z;
        sQ[rb + ((col4 * 4 + 3) ^ x)] = q.w;
    }
    __syncthreads();

    const int count = tileCount[tile];
    const int e0 = t * 16;
    float a1 = 0.f, a2 = 0.f;
    int curBin = -1;

    if (e0 < count) {
        const int4* pe = (const int4*)(perm + tile * TPX + e0);
        #pragma unroll
        for (int g = 0; g < 4; ++g) {
            int4 e4 = pe[g];
            int ee[4] = {e4.x, e4.y, e4.z, e4.w};
            #pragma unroll
            for (int k2 = 0; k2 < 4; ++k2) {
                int idx = e0 + g * 4 + k2;
                if (idx < count) {
                    int e = ee[k2];
                    int bn = e >> 12;
                    int local = e & 4095;
                    int slot = local ^ ((local >> 6) & 31);
                    float n = sP[slot] - sQ[slot];
                    if (bn != curBin) {
                        if (curBin >= 0) {
                            atomicAdd(&h1[curBin], a1);
                            atomicAdd(&h2[curBin], a2);
                        }
                        curBin = bn; a1 = 0.f; a2 = 0.f;
                    }
                    a1 += fabsf(n);
                    a2 += n * n;
                }
            }
        }
        if (curBin >= 0) {
            atomicAdd(&h1[curBin], a1);
            atomicAdd(&h2[curBin], a2);
        }
    }
    __syncthreads();
    if (h1[t] != 0.f) unsafeAtomicAdd(&S1[b * NBINS + t], h1[t]);
    if (h2[t] != 0.f) unsafeAtomicAdd(&S2[b * NBINS + t], h2[t]);
}

// ---- finalize: per-batch closed-form sum over bins ----
__global__ __launch_bounds__(256) void finalize(const float* __restrict__ S1,
                                                const float* __restrict__ S2,
                                                const int* __restrict__ counts,
                                                float* __restrict__ out) {
    const int b = blockIdx.x;
    const int t = threadIdx.x;
    float contrib = 0.f;
    if (t > 3) {   // valid bins 4..255
        float c = (float)counts[t];
        float s1 = S1[b * NBINS + t];
        float s2 = S2[b * NBINS + t];
        float mean = s1 / fmaxf(c, 1.f);
        float ssq = fmaxf(s2 - mean * s1, 0.f);          // = sum (a - mean)^2
        float var = ssq / fmaxf(c - 1.f, 1.f);
        contrib = -0.5f * s2 / var - c * logf(6.283185307179586f * var);
    }
    #pragma unroll
    for (int off = 32; off > 0; off >>= 1) contrib += __shfl_down(contrib, off, 64);
    __shared__ float w[4];
    if ((t & 63) == 0) w[t >> 6] = contrib;
    __syncthreads();
    if (t == 0) out[b] = w[0] + w[1] + w[2] + w[3];
}

extern "C" void kernel_launch(void* const* d_in, const int* in_sizes, int n_in,
                              void* d_out, int out_size, void* d_ws, size_t ws_size,
                              hipStream_t stream) {
    const float* parts = (const float*)d_in[0];
    const float* projs = (const float*)d_in[1];
    const int* bins    = (const int*)d_in[2];
    float* out = (float*)d_out;

    char* ws = (char*)d_ws;
    int*   tileCount = (int*)(ws + 0);
    int*   counts    = (int*)(ws + 512);
    float* S1        = (float*)(ws + 4096);
    float* S2        = (float*)(ws + 135168);
    int*   perm      = (int*)(ws + 266240);

    // zero counts + S1 + S2 (tileCount overwritten unconditionally)
    hipMemsetAsync(d_ws, 0, 266240, stream);

    tilesort<<<NTILES, 256, 0, stream>>>(bins, perm, tileCount, counts);
    pass    <<<dim3(NTILES, NB), 256, 0, stream>>>(parts, projs, perm, tileCount, S1, S2);
    finalize<<<NB, 256, 0, stream>>>(S1, S2, counts, out);
}